// Round 13
// baseline (203.533 us; speedup 1.0000x reference)
//
#include <hip/hip_runtime.h>
#include <hip/hip_fp16.h>
#include <math.h>

// Problem constants
#define HID   1024
#define NHEAD 16
#define HD    64
#define NB    64
#define MAXS  2048
#define CHUNK 256
#define NCH   (MAXS / CHUNK)          // 8
#define PS    68                      // floats per (chunk,b,h) partial record
#define NKS   16                      // proj k-slices

// Non-temporal loads: stream-once data (KV cache, W matrices).
typedef float f4v __attribute__((ext_vector_type(4)));
__device__ __forceinline__ float4 ntload4(const float* p) {
    f4v v = __builtin_nontemporal_load((const f4v*)p);
    return make_float4(v.x, v.y, v.z, v.w);
}
__device__ __forceinline__ float ntloadf(const float* p) {
    return __builtin_nontemporal_load(p);
}

// ---------------------------------------------------------------------------
// Kernel 1a: projection partials, LANE = COLUMN (weights-streaming).
// R12's proj was LDS-broadcast-bound (4096 ds_read_b128/block ~ 20us/CU).
// Here W streams per-lane (coalesced 256B/instr, nt, no LDS); s is read via
// same-address broadcast float4 loads (1 line/request, L2-hot: 48 col-groups
// reuse each line). 1024 waves = 64 colgroups x 16 kslices = 1 wave/SIMD.
// Wave (cg, ks): cols cg*64+lane, k in [ks*64, +64), all 64 batches in regs.
// Writes partial[ks][b][gcol] (16 MB, L2-resident for proj2).
// ---------------------------------------------------------------------------
__global__ __launch_bounds__(256) void proj1_kernel(
    const float* __restrict__ seq, const float* __restrict__ cand,
    const float* __restrict__ Wqkv, const float* __restrict__ Wc,
    float* __restrict__ partial /* [NKS][64][4096] */)
{
    const int tid  = threadIdx.x;
    const int wv   = tid >> 6;
    const int lane = tid & 63;
    const int bid  = blockIdx.x;
    const int cg   = bid & 63;                 // col-group 0..63
    const int ks   = (bid >> 6) * 4 + wv;      // k-slice 0..15
    const int k0   = ks * 64;
    const bool is_qkv = (cg < 48);
    const float* __restrict__ src = is_qkv ? seq  : cand;
    const float* __restrict__ W   = is_qkv ? Wqkv : Wc;
    const int ldw = is_qkv ? 3072 : 1024;
    const int col = is_qkv ? (cg * 64 + lane) : ((cg - 48) * 64 + lane);
    const int gcol = cg * 64 + lane;           // output col 0..4095

    float acc[64];
    #pragma unroll
    for (int b = 0; b < 64; ++b) acc[b] = 0.f;

    const float* wp = W + (size_t)k0 * ldw + col;
    const float* sp = src + k0;

    for (int kq = 0; kq < 16; ++kq) {          // 4 k per iteration
        const float* wq = wp + (size_t)(kq * 4) * ldw;
        float w0 = ntloadf(wq);
        float w1 = ntloadf(wq + ldw);
        float w2 = ntloadf(wq + 2 * (size_t)ldw);
        float w3 = ntloadf(wq + 3 * (size_t)ldw);
        #pragma unroll
        for (int b = 0; b < 64; ++b) {         // static index -> registers
            float4 s4 = *(const float4*)(sp + b * HID + kq * 4);  // uniform addr
            acc[b] = fmaf(s4.x, w0, fmaf(s4.y, w1,
                     fmaf(s4.z, w2, fmaf(s4.w, w3, acc[b]))));
        }
    }

    float* pb = partial + (size_t)(ks * 64) * 4096 + gcol;
    #pragma unroll
    for (int b = 0; b < 64; ++b) pb[(size_t)b * 4096] = acc[b];   // 256B/instr
}

// ---------------------------------------------------------------------------
// Kernel 1b: reduce 16 k-slice partials + bias -> proj ROW-MAJOR [64][4096].
// Partials are L2-resident (16 MB < 32 MB aggregate L2).
// ---------------------------------------------------------------------------
__global__ __launch_bounds__(1024) void proj2_kernel(
    const float* __restrict__ partial, const float* __restrict__ bqkv,
    const float* __restrict__ bcv, float* __restrict__ projRM /* [64][4096] */)
{
    const int T   = blockIdx.x * 1024 + threadIdx.x;
    const int b   = T >> 12;
    const int col = T & 4095;
    float v = (col < 3072) ? bqkv[col] : bcv[col - 3072];
    #pragma unroll
    for (int ks = 0; ks < NKS; ++ks)
        v += partial[(size_t)(ks * 64 + b) * 4096 + col];
    projRM[(size_t)b * 4096 + col] = v;
}

// ---------------------------------------------------------------------------
// Kernel 2: TWO-PHASE chunked attention partials, nt loads (R8 structure,
// measured 6.4 TB/s = read roofline). proj reads updated to row-major.
// ---------------------------------------------------------------------------
__global__ __launch_bounds__(256) void attn_part_kernel(
    const float* __restrict__ projRM, const float* __restrict__ k_cache,
    const float* __restrict__ v_cache, const int* __restrict__ seqlens,
    float* __restrict__ part)
{
    const int idx = blockIdx.x;
    const int c  = idx >> 10;
    const int bh = idx & 1023;
    const int b  = bh >> 4;
    const int h  = bh & 15;
    const int L  = seqlens[b];
    const int s0 = c << 8;
    if (s0 > L) return;

    const int tid = threadIdx.x;
    const int grp = tid >> 4;
    const int gl  = tid & 15;
    const bool has_new = (L < s0 + CHUNK);
    const float* prow = projRM + (size_t)b * 4096 + h * 192;

    __shared__ float lq[64], lk[64], lv[64];
    __shared__ float sm_m[16], sm_l[16];
    __shared__ float sm_o[16][64];

    if (tid < 64) {
        lq[tid] = prow[tid];                       // contiguous
    } else if (tid < 128) {
        if (has_new) {
            int d = tid - 64;
            float kr = prow[64 + d];
            float ss = kr * kr;
            #pragma unroll
            for (int m = 1; m < 64; m <<= 1) ss += __shfl_xor(ss, m);
            float kn = kr / sqrtf(ss);
            lk[d] = __half2float(__float2half_rn(kn));
        }
    } else if (tid < 192) {
        if (has_new) {
            int d = tid - 128;
            lv[d] = prow[128 + d];
        }
    }
    __syncthreads();

    const float4 q4 = ((const float4*)lq)[gl];
    const size_t base0 = (((size_t)b * MAXS) * NHEAD + h) * HD;

    float sc[16];
    float m, l;
    float4 o = make_float4(0.f, 0.f, 0.f, 0.f);

    if (!has_new) {
        #pragma unroll
        for (int t = 0; t < 16; ++t) {
            const int s = s0 + grp + t * 16;
            float4 k4 = ntload4(k_cache + base0 + (size_t)s * (NHEAD * HD) + gl * 4);
            float d = fmaf(k4.x, q4.x, fmaf(k4.y, q4.y, fmaf(k4.z, q4.z, k4.w * q4.w)));
            d += __shfl_xor(d, 1); d += __shfl_xor(d, 2);
            d += __shfl_xor(d, 4); d += __shfl_xor(d, 8);
            sc[t] = d;
        }
        m = sc[0];
        #pragma unroll
        for (int t = 1; t < 16; ++t) m = fmaxf(m, sc[t]);
        l = 0.f;
        #pragma unroll
        for (int t = 0; t < 16; ++t) { float p = __expf(sc[t] - m); sc[t] = p; l += p; }
        #pragma unroll
        for (int t = 0; t < 16; ++t) {
            const int s = s0 + grp + t * 16;
            float4 v4 = ntload4(v_cache + base0 + (size_t)s * (NHEAD * HD) + gl * 4);
            o.x = fmaf(sc[t], v4.x, o.x);
            o.y = fmaf(sc[t], v4.y, o.y);
            o.z = fmaf(sc[t], v4.z, o.z);
            o.w = fmaf(sc[t], v4.w, o.w);
        }
    } else {
        #pragma unroll
        for (int t = 0; t < 16; ++t) {
            const int s = s0 + grp + t * 16;
            float4 k4 = make_float4(0.f, 0.f, 0.f, 0.f);
            if (s < L)       k4 = ntload4(k_cache + base0 + (size_t)s * (NHEAD * HD) + gl * 4);
            else if (s == L) k4 = ((const float4*)lk)[gl];
            float d = fmaf(k4.x, q4.x, fmaf(k4.y, q4.y, fmaf(k4.z, q4.z, k4.w * q4.w)));
            d += __shfl_xor(d, 1); d += __shfl_xor(d, 2);
            d += __shfl_xor(d, 4); d += __shfl_xor(d, 8);
            sc[t] = (s <= L) ? d : -INFINITY;
        }
        m = sc[0];
        #pragma unroll
        for (int t = 1; t < 16; ++t) m = fmaxf(m, sc[t]);
        const float mm = (m == -INFINITY) ? 0.f : m;   // NaN guard (empty group)
        l = 0.f;
        #pragma unroll
        for (int t = 0; t < 16; ++t) { float p = __expf(sc[t] - mm); sc[t] = p; l += p; }
        #pragma unroll
        for (int t = 0; t < 16; ++t) {
            const int s = s0 + grp + t * 16;
            float4 v4 = make_float4(0.f, 0.f, 0.f, 0.f);
            if (s < L)       v4 = ntload4(v_cache + base0 + (size_t)s * (NHEAD * HD) + gl * 4);
            else if (s == L) v4 = ((const float4*)lv)[gl];
            o.x = fmaf(sc[t], v4.x, o.x);
            o.y = fmaf(sc[t], v4.y, o.y);
            o.z = fmaf(sc[t], v4.z, o.z);
            o.w = fmaf(sc[t], v4.w, o.w);
        }
    }

    if (gl == 0) { sm_m[grp] = m; sm_l[grp] = l; }
    ((float4*)sm_o[grp])[gl] = o;
    __syncthreads();

    if (tid < 64) {
        float M = -INFINITY;
        #pragma unroll
        for (int g = 0; g < 16; ++g) M = fmaxf(M, sm_m[g]);
        float li = 0.f, oi = 0.f;
        #pragma unroll
        for (int g = 0; g < 16; ++g) {
            float w = __expf(sm_m[g] - M);
            li += w * sm_l[g];
            oi += w * sm_o[g][tid];
        }
        float* pb = part + (size_t)(c * 1024 + bh) * PS;
        pb[tid] = oi;
        if (tid == 0) { pb[64] = M; pb[65] = li; }
    }
}

// ---------------------------------------------------------------------------
// Kernel 3: merge <=8 chunk partials per (b,h). 1024 blocks x 64 threads.
// ---------------------------------------------------------------------------
__global__ __launch_bounds__(64) void attn_merge_kernel(
    const float* __restrict__ part, const int* __restrict__ seqlens,
    float* __restrict__ attn_out /* [1024][64] col-major */)
{
    const int bh = blockIdx.x;
    const int b  = bh >> 4;
    const int h  = bh & 15;
    const int d  = threadIdx.x;
    const int nch = (seqlens[b] >> 8) + 1;

    float M = -INFINITY, l = 0.f, o = 0.f;
    for (int c = 0; c < nch; ++c) {
        const float* pb = part + (size_t)(c * 1024 + bh) * PS;
        float mc = pb[64], lc = pb[65];
        float Mn = fmaxf(M, mc);
        float f = __expf(M - Mn);
        float w = __expf(mc - Mn);
        o = o * f + w * pb[d];
        l = l * f + w * lc;
        M = Mn;
    }
    attn_out[(h * 64 + d) * 64 + b] = o / l;
}

// ---------------------------------------------------------------------------
// Kernel 4: postx = attn @ Wo + bo (unchanged — Wo read exactly once)
// ---------------------------------------------------------------------------
__global__ __launch_bounds__(1024) void wo_kernel(
    const float* __restrict__ attn_s, const float* __restrict__ Wo,
    const float* __restrict__ bo, float* __restrict__ postx /* [1024][64] */)
{
    const int tid  = threadIdx.x;
    const int wv   = __builtin_amdgcn_readfirstlane(tid >> 6);
    const int lane = tid & 63;
    const int c0   = blockIdx.x * 8;
    const int k0   = wv * 64;

    float acc[8];
    #pragma unroll
    for (int j = 0; j < 8; ++j) acc[j] = 0.f;

    for (int k = 0; k < 64; ++k) {
        float sv = attn_s[(k0 + k) * 64 + lane];
        const float4* wr = (const float4*)(Wo + (size_t)(k0 + k) * 1024 + c0);
        float4 w0 = wr[0], w1 = wr[1];
        acc[0] = fmaf(sv, w0.x, acc[0]); acc[1] = fmaf(sv, w0.y, acc[1]);
        acc[2] = fmaf(sv, w0.z, acc[2]); acc[3] = fmaf(sv, w0.w, acc[3]);
        acc[4] = fmaf(sv, w1.x, acc[4]); acc[5] = fmaf(sv, w1.y, acc[5]);
        acc[6] = fmaf(sv, w1.z, acc[6]); acc[7] = fmaf(sv, w1.w, acc[7]);
    }

    __shared__ float red[16][8][64];
    #pragma unroll
    for (int j = 0; j < 8; ++j) red[wv][j][lane] = acc[j];
    __syncthreads();

    if (tid < 512) {
        const int j = tid >> 6, b = tid & 63;
        float s = 0.f;
        #pragma unroll
        for (int w = 0; w < 16; ++w) s += red[w][j][b];
        postx[(c0 + j) * 64 + b] = s + bo[c0 + j];
    }
}

// ---------------------------------------------------------------------------
// Kernel 5: dual LayerNorm (cand read updated to row-major proj)
// ---------------------------------------------------------------------------
__global__ __launch_bounds__(256) void ln_kernel(
    const float* __restrict__ seq, const float* __restrict__ projRM,
    const float* __restrict__ postx, const float* __restrict__ gamma,
    const float* __restrict__ beta, float* __restrict__ out)
{
    const int b   = blockIdx.x;
    const int tid = threadIdx.x;
    float x1[4], x2[4];
    float s1 = 0.f, q1 = 0.f, s2 = 0.f, q2 = 0.f;

    #pragma unroll
    for (int i = 0; i < 4; ++i) {
        int c = tid + i * 256;
        float px = postx[c * 64 + b];
        float sv = seq[b * HID + c];
        float cd = projRM[(size_t)b * 4096 + 3072 + c];   // contiguous
        float a = sv + px, d = px + cd;
        x1[i] = a; x2[i] = d;
        s1 += a; q1 += a * a; s2 += d; q2 += d * d;
    }
    #pragma unroll
    for (int m = 1; m < 64; m <<= 1) {
        s1 += __shfl_xor(s1, m); q1 += __shfl_xor(q1, m);
        s2 += __shfl_xor(s2, m); q2 += __shfl_xor(q2, m);
    }
    __shared__ float rsm[4][4];
    const int wv = tid >> 6, lane = tid & 63;
    if (lane == 0) { rsm[wv][0] = s1; rsm[wv][1] = q1; rsm[wv][2] = s2; rsm[wv][3] = q2; }
    __syncthreads();

    float S1 = rsm[0][0] + rsm[1][0] + rsm[2][0] + rsm[3][0];
    float Q1 = rsm[0][1] + rsm[1][1] + rsm[2][1] + rsm[3][1];
    float S2 = rsm[0][2] + rsm[1][2] + rsm[2][2] + rsm[3][2];
    float Q2 = rsm[0][3] + rsm[1][3] + rsm[2][3] + rsm[3][3];

    const float inv = 1.f / 1024.f;
    float mu1 = S1 * inv, v1 = Q1 * inv - mu1 * mu1;
    float mu2 = S2 * inv, v2 = Q2 * inv - mu2 * mu2;
    float r1 = rsqrtf(v1 + 1e-5f);
    float r2 = rsqrtf(v2 + 1e-5f);

    #pragma unroll
    for (int i = 0; i < 4; ++i) {
        int c = tid + i * 256;
        float g = gamma[c], be = beta[c];
        out[b * HID + c]            = (x1[i] - mu1) * r1 * g + be;   // seq_out
        out[NB * HID + b * HID + c] = (x2[i] - mu2) * r2 * g + be;   // candidate_out
    }
}

// ---------------------------------------------------------------------------
extern "C" void kernel_launch(void* const* d_in, const int* in_sizes, int n_in,
                              void* d_out, int out_size, void* d_ws, size_t ws_size,
                              hipStream_t stream) {
    const float* seq      = (const float*)d_in[0];
    const float* cand     = (const float*)d_in[1];
    const float* k_cache  = (const float*)d_in[2];
    const float* v_cache  = (const float*)d_in[3];
    const int*   seqlens  = (const int*)  d_in[4];
    const float* Wqkv     = (const float*)d_in[5];
    const float* bqkv     = (const float*)d_in[6];
    const float* Wc       = (const float*)d_in[7];
    const float* bcv      = (const float*)d_in[8];
    const float* Wo       = (const float*)d_in[9];
    const float* bo       = (const float*)d_in[10];
    const float* gamma    = (const float*)d_in[11];
    const float* beta     = (const float*)d_in[12];
    float* out = (float*)d_out;

    float* ws      = (float*)d_ws;
    float* projRM  = ws;                          // [64][4096]      = 262144 f
    float* attn    = projRM + 64 * 4096;          // [1024][64]      =  65536 f
    float* postx   = attn   + 1024 * 64;          // [1024][64]      =  65536 f
    float* part    = postx  + 1024 * 64;          // [8*1024][PS]    = 557056 f
    float* partial = part   + NCH * 1024 * PS;    // [16][64][4096]  = 4194304 f (16 MB)

    proj1_kernel     <<<256, 256, 0, stream>>>(seq, cand, Wqkv, Wc, partial);
    proj2_kernel     <<<256, 1024, 0, stream>>>(partial, bqkv, bcv, projRM);
    attn_part_kernel <<<NCH * 1024, 256, 0, stream>>>(projRM, k_cache, v_cache, seqlens, part);
    attn_merge_kernel<<<NB * NHEAD, 64, 0, stream>>>(part, seqlens, attn);
    wo_kernel        <<<128, 1024, 0, stream>>>(attn, Wo, bo, postx);
    ln_kernel        <<<NB, 256, 0, stream>>>(seq, projRM, postx, gamma, beta, out);
}

// Round 14
// 136.414 us; speedup vs baseline: 1.4920x; 1.4920x over previous
//
#include <hip/hip_runtime.h>
#include <hip/hip_fp16.h>
#include <math.h>

// Problem constants
#define HID   1024
#define NHEAD 16
#define HD    64
#define NB    64
#define MAXS  2048
#define CHUNK 256
#define NCH   (MAXS / CHUNK)          // 8
#define PS    68                      // floats per (chunk,b,h) partial record
#define NKS   16                      // proj k-slices

// Non-temporal loads: stream-once data (KV cache, W matrices).
typedef float f4v __attribute__((ext_vector_type(4)));
__device__ __forceinline__ float4 ntload4(const float* p) {
    f4v v = __builtin_nontemporal_load((const f4v*)p);
    return make_float4(v.x, v.y, v.z, v.w);
}
__device__ __forceinline__ float ntloadf(const float* p) {
    return __builtin_nontemporal_load(p);
}

// ---------------------------------------------------------------------------
// Kernel 1a: projection partials, lane=COLUMN, s staged in LDS.
// R13's version read s via wave-uniform GLOBAL loads -> scalar-path serialization
// (same hazard as R10's W loads) at 1 wave/SIMD -> ~90us. Fix (only change):
// s comes from LDS via broadcast ds_read_b128 (vector path, conflict-free),
// W streams per-lane coalesced nt (256B/instr, no LDS round-trip), and the
// grid is 1024 blocks x 256 thr (4 blocks/CU, 16 waves/CU) for latency hiding.
// Block (cg, ks): cols cg*64..+63, k in [ks*64,+64); wave wv owns 16 k-rows.
// ---------------------------------------------------------------------------
__global__ __launch_bounds__(256) void proj1_kernel(
    const float* __restrict__ seq, const float* __restrict__ cand,
    const float* __restrict__ Wqkv, const float* __restrict__ Wc,
    float* __restrict__ partial /* [NKS][64][4096] */)
{
    const int tid  = threadIdx.x;
    const int wv   = tid >> 6;
    const int lane = tid & 63;
    const int bid  = blockIdx.x;
    const int cg   = bid & 63;                 // col-group 0..63
    const int ks   = bid >> 6;                 // k-slice 0..15
    const int k0   = ks * 64;
    const bool is_qkv = (cg < 48);
    const float* __restrict__ src = is_qkv ? seq  : cand;
    const float* __restrict__ W   = is_qkv ? Wqkv : Wc;
    const int ldw  = is_qkv ? 3072 : 1024;
    const int col  = (is_qkv ? cg * 64 : (cg - 48) * 64) + lane;
    const int gcol = cg * 64 + lane;           // output col 0..4095

    __shared__ float s_lds[64][68];            // [b][k] + pad (write-conflict-free)

    // ---- stage s slice [64 b][64 k]: coalesced float4 per thread ----
    {
        const int b = tid >> 2, q = tid & 3;
        const float* sb = src + b * HID + k0;
        #pragma unroll
        for (int i = 0; i < 4; ++i) {
            const int kk = (q + i * 4) * 4;
            *(float4*)&s_lds[b][kk] = *(const float4*)(sb + kk);
        }
    }
    __syncthreads();

    // ---- preload this wave's 16 W rows for its column (coalesced, nt) ----
    const int kw = wv * 16;                    // wave's k-offset within slice
    float w[16];
    const float* wp = W + (size_t)(k0 + kw) * ldw + col;
    #pragma unroll
    for (int i = 0; i < 16; ++i) w[i] = ntloadf(wp + (size_t)i * ldw);

    // ---- accumulate over all 64 batches (broadcast s from LDS) ----
    float acc[64];
    #pragma unroll
    for (int b = 0; b < 64; ++b) acc[b] = 0.f;

    #pragma unroll
    for (int kq = 0; kq < 4; ++kq) {
        #pragma unroll
        for (int b = 0; b < 64; ++b) {
            float4 s4 = *(const float4*)&s_lds[b][kw + kq * 4];   // broadcast
            acc[b] = fmaf(s4.x, w[kq*4+0], fmaf(s4.y, w[kq*4+1],
                     fmaf(s4.z, w[kq*4+2], fmaf(s4.w, w[kq*4+3], acc[b]))));
        }
    }

    // ---- write partial[ks][b][gcol]: wave-contiguous 256B stores ----
    // 4 waves write the same [b][gcol-range] for different ks?? no: same ks,
    // different kw -> MUST be reduced across waves first. Use LDS reduce.
    __syncthreads();                            // re-use s_lds as reduce buffer
    // wave-partial reduction: wave wv adds its acc into s_lds-backed buffer.
    // Layout: red[b][lane] accumulated sequentially by wave order.
    {
        __shared__ float red[64][68];
        if (wv == 0) {
            #pragma unroll
            for (int b = 0; b < 64; ++b) red[b][lane] = acc[b];
        }
        __syncthreads();
        if (wv == 1) {
            #pragma unroll
            for (int b = 0; b < 64; ++b) red[b][lane] += acc[b];
        }
        __syncthreads();
        if (wv == 2) {
            #pragma unroll
            for (int b = 0; b < 64; ++b) red[b][lane] += acc[b];
        }
        __syncthreads();
        if (wv == 3) {
            #pragma unroll
            for (int b = 0; b < 64; ++b) red[b][lane] += acc[b];
        }
        __syncthreads();

        // 256 threads write 64x64 results: thread t -> rows b = t>>2 span
        {
            const int b = tid >> 2, q = tid & 3;
            float* pb = partial + (size_t)(ks * 64 + b) * 4096 + cg * 64;
            #pragma unroll
            for (int i = 0; i < 4; ++i) {
                const int c = (q + i * 4) * 4;
                *(float4*)(pb + c) = *(const float4*)&red[b][c];
            }
        }
    }
}

// ---------------------------------------------------------------------------
// Kernel 1b: reduce 16 k-slice partials + bias -> proj ROW-MAJOR [64][4096].
// Partials are L2-resident (16 MB < 32 MB aggregate L2).
// ---------------------------------------------------------------------------
__global__ __launch_bounds__(1024) void proj2_kernel(
    const float* __restrict__ partial, const float* __restrict__ bqkv,
    const float* __restrict__ bcv, float* __restrict__ projRM /* [64][4096] */)
{
    const int T   = blockIdx.x * 1024 + threadIdx.x;
    const int b   = T >> 12;
    const int col = T & 4095;
    float v = (col < 3072) ? bqkv[col] : bcv[col - 3072];
    #pragma unroll
    for (int ks = 0; ks < NKS; ++ks)
        v += partial[(size_t)(ks * 64 + b) * 4096 + col];
    projRM[(size_t)b * 4096 + col] = v;
}

// ---------------------------------------------------------------------------
// Kernel 2: TWO-PHASE chunked attention partials, nt loads (R8 structure,
// measured 6.4 TB/s = read roofline). Row-major proj reads (R13, verified).
// ---------------------------------------------------------------------------
__global__ __launch_bounds__(256) void attn_part_kernel(
    const float* __restrict__ projRM, const float* __restrict__ k_cache,
    const float* __restrict__ v_cache, const int* __restrict__ seqlens,
    float* __restrict__ part)
{
    const int idx = blockIdx.x;
    const int c  = idx >> 10;
    const int bh = idx & 1023;
    const int b  = bh >> 4;
    const int h  = bh & 15;
    const int L  = seqlens[b];
    const int s0 = c << 8;
    if (s0 > L) return;

    const int tid = threadIdx.x;
    const int grp = tid >> 4;
    const int gl  = tid & 15;
    const bool has_new = (L < s0 + CHUNK);
    const float* prow = projRM + (size_t)b * 4096 + h * 192;

    __shared__ float lq[64], lk[64], lv[64];
    __shared__ float sm_m[16], sm_l[16];
    __shared__ float sm_o[16][64];

    if (tid < 64) {
        lq[tid] = prow[tid];
    } else if (tid < 128) {
        if (has_new) {
            int d = tid - 64;
            float kr = prow[64 + d];
            float ss = kr * kr;
            #pragma unroll
            for (int m = 1; m < 64; m <<= 1) ss += __shfl_xor(ss, m);
            float kn = kr / sqrtf(ss);
            lk[d] = __half2float(__float2half_rn(kn));
        }
    } else if (tid < 192) {
        if (has_new) {
            int d = tid - 128;
            lv[d] = prow[128 + d];
        }
    }
    __syncthreads();

    const float4 q4 = ((const float4*)lq)[gl];
    const size_t base0 = (((size_t)b * MAXS) * NHEAD + h) * HD;

    float sc[16];
    float m, l;
    float4 o = make_float4(0.f, 0.f, 0.f, 0.f);

    if (!has_new) {
        #pragma unroll
        for (int t = 0; t < 16; ++t) {
            const int s = s0 + grp + t * 16;
            float4 k4 = ntload4(k_cache + base0 + (size_t)s * (NHEAD * HD) + gl * 4);
            float d = fmaf(k4.x, q4.x, fmaf(k4.y, q4.y, fmaf(k4.z, q4.z, k4.w * q4.w)));
            d += __shfl_xor(d, 1); d += __shfl_xor(d, 2);
            d += __shfl_xor(d, 4); d += __shfl_xor(d, 8);
            sc[t] = d;
        }
        m = sc[0];
        #pragma unroll
        for (int t = 1; t < 16; ++t) m = fmaxf(m, sc[t]);
        l = 0.f;
        #pragma unroll
        for (int t = 0; t < 16; ++t) { float p = __expf(sc[t] - m); sc[t] = p; l += p; }
        #pragma unroll
        for (int t = 0; t < 16; ++t) {
            const int s = s0 + grp + t * 16;
            float4 v4 = ntload4(v_cache + base0 + (size_t)s * (NHEAD * HD) + gl * 4);
            o.x = fmaf(sc[t], v4.x, o.x);
            o.y = fmaf(sc[t], v4.y, o.y);
            o.z = fmaf(sc[t], v4.z, o.z);
            o.w = fmaf(sc[t], v4.w, o.w);
        }
    } else {
        #pragma unroll
        for (int t = 0; t < 16; ++t) {
            const int s = s0 + grp + t * 16;
            float4 k4 = make_float4(0.f, 0.f, 0.f, 0.f);
            if (s < L)       k4 = ntload4(k_cache + base0 + (size_t)s * (NHEAD * HD) + gl * 4);
            else if (s == L) k4 = ((const float4*)lk)[gl];
            float d = fmaf(k4.x, q4.x, fmaf(k4.y, q4.y, fmaf(k4.z, q4.z, k4.w * q4.w)));
            d += __shfl_xor(d, 1); d += __shfl_xor(d, 2);
            d += __shfl_xor(d, 4); d += __shfl_xor(d, 8);
            sc[t] = (s <= L) ? d : -INFINITY;
        }
        m = sc[0];
        #pragma unroll
        for (int t = 1; t < 16; ++t) m = fmaxf(m, sc[t]);
        const float mm = (m == -INFINITY) ? 0.f : m;   // NaN guard (empty group)
        l = 0.f;
        #pragma unroll
        for (int t = 0; t < 16; ++t) { float p = __expf(sc[t] - mm); sc[t] = p; l += p; }
        #pragma unroll
        for (int t = 0; t < 16; ++t) {
            const int s = s0 + grp + t * 16;
            float4 v4 = make_float4(0.f, 0.f, 0.f, 0.f);
            if (s < L)       v4 = ntload4(v_cache + base0 + (size_t)s * (NHEAD * HD) + gl * 4);
            else if (s == L) v4 = ((const float4*)lv)[gl];
            o.x = fmaf(sc[t], v4.x, o.x);
            o.y = fmaf(sc[t], v4.y, o.y);
            o.z = fmaf(sc[t], v4.z, o.z);
            o.w = fmaf(sc[t], v4.w, o.w);
        }
    }

    if (gl == 0) { sm_m[grp] = m; sm_l[grp] = l; }
    ((float4*)sm_o[grp])[gl] = o;
    __syncthreads();

    if (tid < 64) {
        float M = -INFINITY;
        #pragma unroll
        for (int g = 0; g < 16; ++g) M = fmaxf(M, sm_m[g]);
        float li = 0.f, oi = 0.f;
        #pragma unroll
        for (int g = 0; g < 16; ++g) {
            float w = __expf(sm_m[g] - M);
            li += w * sm_l[g];
            oi += w * sm_o[g][tid];
        }
        float* pb = part + (size_t)(c * 1024 + bh) * PS;
        pb[tid] = oi;
        if (tid == 0) { pb[64] = M; pb[65] = li; }
    }
}

// ---------------------------------------------------------------------------
// Kernel 3: merge <=8 chunk partials per (b,h). 1024 blocks x 64 threads.
// ---------------------------------------------------------------------------
__global__ __launch_bounds__(64) void attn_merge_kernel(
    const float* __restrict__ part, const int* __restrict__ seqlens,
    float* __restrict__ attn_out /* [1024][64] col-major */)
{
    const int bh = blockIdx.x;
    const int b  = bh >> 4;
    const int h  = bh & 15;
    const int d  = threadIdx.x;
    const int nch = (seqlens[b] >> 8) + 1;

    float M = -INFINITY, l = 0.f, o = 0.f;
    for (int c = 0; c < nch; ++c) {
        const float* pb = part + (size_t)(c * 1024 + bh) * PS;
        float mc = pb[64], lc = pb[65];
        float Mn = fmaxf(M, mc);
        float f = __expf(M - Mn);
        float w = __expf(mc - Mn);
        o = o * f + w * pb[d];
        l = l * f + w * lc;
        M = Mn;
    }
    attn_out[(h * 64 + d) * 64 + b] = o / l;
}

// ---------------------------------------------------------------------------
// Kernel 4: postx = attn @ Wo + bo (unchanged — Wo read exactly once)
// ---------------------------------------------------------------------------
__global__ __launch_bounds__(1024) void wo_kernel(
    const float* __restrict__ attn_s, const float* __restrict__ Wo,
    const float* __restrict__ bo, float* __restrict__ postx /* [1024][64] */)
{
    const int tid  = threadIdx.x;
    const int wv   = __builtin_amdgcn_readfirstlane(tid >> 6);
    const int lane = tid & 63;
    const int c0   = blockIdx.x * 8;
    const int k0   = wv * 64;

    float acc[8];
    #pragma unroll
    for (int j = 0; j < 8; ++j) acc[j] = 0.f;

    for (int k = 0; k < 64; ++k) {
        float sv = attn_s[(k0 + k) * 64 + lane];
        const float4* wr = (const float4*)(Wo + (size_t)(k0 + k) * 1024 + c0);
        float4 w0 = wr[0], w1 = wr[1];
        acc[0] = fmaf(sv, w0.x, acc[0]); acc[1] = fmaf(sv, w0.y, acc[1]);
        acc[2] = fmaf(sv, w0.z, acc[2]); acc[3] = fmaf(sv, w0.w, acc[3]);
        acc[4] = fmaf(sv, w1.x, acc[4]); acc[5] = fmaf(sv, w1.y, acc[5]);
        acc[6] = fmaf(sv, w1.z, acc[6]); acc[7] = fmaf(sv, w1.w, acc[7]);
    }

    __shared__ float red[16][8][64];
    #pragma unroll
    for (int j = 0; j < 8; ++j) red[wv][j][lane] = acc[j];
    __syncthreads();

    if (tid < 512) {
        const int j = tid >> 6, b = tid & 63;
        float s = 0.f;
        #pragma unroll
        for (int w = 0; w < 16; ++w) s += red[w][j][b];
        postx[(c0 + j) * 64 + b] = s + bo[c0 + j];
    }
}

// ---------------------------------------------------------------------------
// Kernel 5: dual LayerNorm (row-major proj reads, R13, verified)
// ---------------------------------------------------------------------------
__global__ __launch_bounds__(256) void ln_kernel(
    const float* __restrict__ seq, const float* __restrict__ projRM,
    const float* __restrict__ postx, const float* __restrict__ gamma,
    const float* __restrict__ beta, float* __restrict__ out)
{
    const int b   = blockIdx.x;
    const int tid = threadIdx.x;
    float x1[4], x2[4];
    float s1 = 0.f, q1 = 0.f, s2 = 0.f, q2 = 0.f;

    #pragma unroll
    for (int i = 0; i < 4; ++i) {
        int c = tid + i * 256;
        float px = postx[c * 64 + b];
        float sv = seq[b * HID + c];
        float cd = projRM[(size_t)b * 4096 + 3072 + c];
        float a = sv + px, d = px + cd;
        x1[i] = a; x2[i] = d;
        s1 += a; q1 += a * a; s2 += d; q2 += d * d;
    }
    #pragma unroll
    for (int m = 1; m < 64; m <<= 1) {
        s1 += __shfl_xor(s1, m); q1 += __shfl_xor(q1, m);
        s2 += __shfl_xor(s2, m); q2 += __shfl_xor(q2, m);
    }
    __shared__ float rsm[4][4];
    const int wv = tid >> 6, lane = tid & 63;
    if (lane == 0) { rsm[wv][0] = s1; rsm[wv][1] = q1; rsm[wv][2] = s2; rsm[wv][3] = q2; }
    __syncthreads();

    float S1 = rsm[0][0] + rsm[1][0] + rsm[2][0] + rsm[3][0];
    float Q1 = rsm[0][1] + rsm[1][1] + rsm[2][1] + rsm[3][1];
    float S2 = rsm[0][2] + rsm[1][2] + rsm[2][2] + rsm[3][2];
    float Q2 = rsm[0][3] + rsm[1][3] + rsm[2][3] + rsm[3][3];

    const float inv = 1.f / 1024.f;
    float mu1 = S1 * inv, v1 = Q1 * inv - mu1 * mu1;
    float mu2 = S2 * inv, v2 = Q2 * inv - mu2 * mu2;
    float r1 = rsqrtf(v1 + 1e-5f);
    float r2 = rsqrtf(v2 + 1e-5f);

    #pragma unroll
    for (int i = 0; i < 4; ++i) {
        int c = tid + i * 256;
        float g = gamma[c], be = beta[c];
        out[b * HID + c]            = (x1[i] - mu1) * r1 * g + be;   // seq_out
        out[NB * HID + b * HID + c] = (x2[i] - mu2) * r2 * g + be;   // candidate_out
    }
}

// ---------------------------------------------------------------------------
extern "C" void kernel_launch(void* const* d_in, const int* in_sizes, int n_in,
                              void* d_out, int out_size, void* d_ws, size_t ws_size,
                              hipStream_t stream) {
    const float* seq      = (const float*)d_in[0];
    const float* cand     = (const float*)d_in[1];
    const float* k_cache  = (const float*)d_in[2];
    const float* v_cache  = (const float*)d_in[3];
    const int*   seqlens  = (const int*)  d_in[4];
    const float* Wqkv     = (const float*)d_in[5];
    const float* bqkv     = (const float*)d_in[6];
    const float* Wc       = (const float*)d_in[7];
    const float* bcv      = (const float*)d_in[8];
    const float* Wo       = (const float*)d_in[9];
    const float* bo       = (const float*)d_in[10];
    const float* gamma    = (const float*)d_in[11];
    const float* beta     = (const float*)d_in[12];
    float* out = (float*)d_out;

    float* ws      = (float*)d_ws;
    float* projRM  = ws;                          // [64][4096]      = 262144 f
    float* attn    = projRM + 64 * 4096;          // [1024][64]      =  65536 f
    float* postx   = attn   + 1024 * 64;          // [1024][64]      =  65536 f
    float* part    = postx  + 1024 * 64;          // [8*1024][PS]    = 557056 f
    float* partial = part   + NCH * 1024 * PS;    // [16][64][4096]  = 4194304 f (16 MB)

    proj1_kernel     <<<1024, 256, 0, stream>>>(seq, cand, Wqkv, Wc, partial);
    proj2_kernel     <<<256, 1024, 0, stream>>>(partial, bqkv, bcv, projRM);
    attn_part_kernel <<<NCH * 1024, 256, 0, stream>>>(projRM, k_cache, v_cache, seqlens, part);
    attn_merge_kernel<<<NB * NHEAD, 64, 0, stream>>>(part, seqlens, attn);
    wo_kernel        <<<128, 1024, 0, stream>>>(attn, Wo, bo, postx);
    ln_kernel        <<<NB, 256, 0, stream>>>(seq, projRM, postx, gamma, beta, out);
}